// Round 9
// baseline (171.800 us; speedup 1.0000x reference)
//
#include <hip/hip_runtime.h>
#include <stdint.h>

#define IN_C   128
#define OUT_C  128
#define KTOT   1152      // IN_C*3*3
#define NG     8
#define NW     8
#define NB     8
#define HH     56
#define WWID   56
#define NPIX   3136
#define MTOT   1024      // OUT_C*NW
#define HALO   58        // 56 + zero border on each side
#define HPIX   (HALO*HALO)   // 3364

// k-order SPATIAL-MAJOR: k' = s*128 + c, s = kh*3+kw.
// B gathered from zero-halo Xt[b][58*58][128c] bf16, staged via LDS (BK=32,
// 2x8KB dbuf, 36 fully-unrolled stages, 1 barrier each; A-frags issued in
// stage st are consumed after the next barrier -> latency always covered).
// A pre-packed FRAGMENT-LINEAR Apack[m16][kt][lq][lr][8e]; direct global->VGPR.
// Routing + softmax + blend fused into the gemm (s-table in LDS).

typedef __attribute__((ext_vector_type(8))) short short8;
typedef __attribute__((ext_vector_type(8))) unsigned short ushort8;
typedef __attribute__((ext_vector_type(4))) float f32x4;

__device__ __forceinline__ unsigned short f2bf(float f) {
    unsigned u = __float_as_uint(f);
    u += 0x7FFF + ((u >> 16) & 1);          // round-to-nearest-even
    return (unsigned short)(u >> 16);
}

__device__ __forceinline__ void cp16(const unsigned short* g, unsigned short* l) {
    __builtin_amdgcn_global_load_lds(
        (const __attribute__((address_space(1))) unsigned int*)g,
        (__attribute__((address_space(3))) unsigned int*)l,
        16, 0, 0);
}

// ---------- 1) fused prep: gap (0..1023) | tconv/pack (1024..1151) | transpose (1152..1375) ----------
__global__ __launch_bounds__(256) void prep_kernel(const float* __restrict__ in,
                                                   const float* __restrict__ T,
                                                   float* __restrict__ xse,
                                                   unsigned short* __restrict__ Apack,
                                                   unsigned short* __restrict__ Xt) {
    __shared__ __align__(16) unsigned char smem[32768];   // 32 KB -> 5 blocks/CU
    const int blk = blockIdx.x;
    const int t = threadIdx.x;

    if (blk < 1024) {
        // ---- global average pool: xse[b,c] ----
        const float* src = in + (size_t)blk * NPIX;
        float s = 0.f;
        for (int i = t; i < NPIX / 4; i += 256) {
            float4 v = ((const float4*)src)[i];
            s += v.x + v.y + v.z + v.w;
        }
        #pragma unroll
        for (int off = 32; off; off >>= 1) s += __shfl_down(s, off);
        float* ws4 = (float*)smem;
        if ((t & 63) == 0) ws4[t >> 6] = s;
        __syncthreads();
        if (t == 0)
            xse[blk] = (ws4[0] + ws4[1] + ws4[2] + ws4[3]) * (1.0f / (float)NPIX);
        return;
    }
    if (blk < 1152) {
        // ---- tconv+pack: block per o. T[o][k][j] slab -> bf16 LDS (18 KB) ->
        //      fragment-linear Apack[m16][kt][lq][lr][8e].
        unsigned short* lh = (unsigned short*)smem;  // 9216 bf16 = 18 KB
        const int o = blk - 1024;
        const float* To = T + (size_t)o * 9216;
        #pragma unroll
        for (int it = 0; it < 9; it++) {
            const int f = it * 256 + t;              // 0..2303 float4 units
            const float4 v = ((const float4*)To)[f];
            ushort4 h;
            h.x = f2bf(v.x); h.y = f2bf(v.y); h.z = f2bf(v.z); h.w = f2bf(v.w);
            *(ushort4*)&lh[f * 4] = h;
        }
        __syncthreads();
        const int m16b = o >> 1;
        const int lrb = (o & 1) * 8;
        #pragma unroll
        for (int it = 0; it < 5; it++) {
            const int ch = it * 256 + t;             // 0..1151: ch = kc*8 + j
            if (ch < 1152) {
                const int j = ch & 7, kc = ch >> 3;  // kc = k-octet 0..143
                const int s = kc >> 4, c0 = (kc & 15) << 3;
                const int kt = kc >> 2, lq = kc & 3;
                ushort8 v;
                #pragma unroll
                for (int i = 0; i < 8; i++)
                    v[i] = lh[((c0 + i) * 9 + s) * 8 + j];
                const size_t off = ((((size_t)m16b * 36 + kt) * 4 + lq) * 16 + lrb + j) * 8;
                *(ushort8*)&Apack[off] = v;
            }
        }
        return;
    }
    // ---- transpose: in[b][c][y][x] fp32 -> Xt[b][(y+1)*58+(x+1)][c] bf16, zero halo ----
    unsigned short* tile = (unsigned short*)smem;    // 32 KB, [c][pix 0..112)
    const int idx = blk - 1152;                      // 0..223
    const int yt = idx % 28;
    const int b  = idx / 28;
    const int y0 = yt * 2;

    #pragma unroll
    for (int it = 0; it < 14; it++) {
        const int f = it * 256 + t;
        const int c = f / 28;
        const int rem = f - c * 28;
        const int y = rem / 14;
        const int x4 = rem - y * 14;
        const float4 v = *(const float4*)(in + ((size_t)(b * IN_C + c)) * NPIX
                                          + (y0 + y) * WWID + x4 * 4);
        unsigned short bf0 = f2bf(v.x), bf1 = f2bf(v.y), bf2 = f2bf(v.z), bf3 = f2bf(v.w);
        const int ppb = (y * WWID + x4 * 4) ^ (((c >> 3) & 15) << 2);
        uint2 pk;
        pk.x = (unsigned)bf0 | ((unsigned)bf1 << 16);
        pk.y = (unsigned)bf2 | ((unsigned)bf3 << 16);
        *(uint2*)&tile[c * 128 + ppb] = pk;
    }
    __syncthreads();

    #pragma unroll
    for (int it = 0; it < 7; it++) {
        const int ch = it * 256 + t;
        const int oct = ch & 15;
        const int pp = ch >> 4;
        const int sw = oct << 2;
        ushort8 v;
        #pragma unroll
        for (int i = 0; i < 8; i++)
            v[i] = tile[(oct * 8 + i) * 128 + (pp ^ sw)];
        const int y2 = (pp >= WWID) ? 1 : 0;
        const int xg = pp - y2 * WWID;
        const size_t hp = (size_t)b * HPIX + (y0 + y2 + 1) * HALO + (xg + 1);
        *(ushort8*)&Xt[hp * 128 + oct * 8] = v;
    }

    if (t < 64) {   // halo columns xx=0,57 for this block's two rows
        const int pi = t >> 4, oct = t & 15;
        const int yy = y0 + 1 + (pi >> 1);
        const int xx = (pi & 1) * 57;
        *(ushort8*)&Xt[((size_t)b * HPIX + yy * HALO + xx) * 128 + oct * 8] =
            (ushort8){0, 0, 0, 0, 0, 0, 0, 0};
    }
    if (yt == 0 || yt == 27) {   // halo rows yy=0 / 57
        const int yy = (yt == 0) ? 0 : 57;
        #pragma unroll
        for (int it = 0; it < 4; it++) {
            const int ch = it * 256 + t;
            if (ch < 928) {
                const int xx = ch >> 4, oct = ch & 15;
                *(ushort8*)&Xt[((size_t)b * HPIX + yy * HALO + xx) * 128 + oct * 8] =
                    (ushort8){0, 0, 0, 0, 0, 0, 0, 0};
            }
        }
    }
}

// ---------- 2) main GEMM + fused routing/softmax/blend ----------
// BK=32 ping-pong (the measured-best latency structure), 36 stages fully
// unrolled so all offsets are compile-time constants (kills address VALU).
__global__ __launch_bounds__(256) void gemm_kernel(const unsigned short* __restrict__ Apack,
                                                   const unsigned short* __restrict__ Xt,
                                                   const float* __restrict__ xse,
                                                   const float* __restrict__ rw,
                                                   const float* __restrict__ rb,
                                                   const float* __restrict__ Alpha,
                                                   const int* __restrict__ mask,
                                                   const int* __restrict__ use_alpha,
                                                   const float* __restrict__ bias,
                                                   float* __restrict__ out) {
    __shared__ __align__(16) unsigned short Bsh[2][512 * 8];   // 2 x 8 KB
    __shared__ float ssh[128 * 8];                             // 4 KB s-table
    __shared__ float xs[IN_C];
    __shared__ float rsh[64];

    const int tid = threadIdx.x;
    const int wv = tid >> 6, ln = tid & 63;
    const int lq = ln >> 4, lr = ln & 15;
    const int wrow = wv >> 1, wcol = wv & 1;

    const int lid = blockIdx.x;            // 0..1599
    const int b   = lid & 7;               // XCD = b
    const int sl  = lid >> 3;              // 0..199
    const int mt  = sl & 7;
    const int nt  = sl >> 3;               // 0..24

    // B staging: chunk (r, slot js) holds octet q = js ^ (r&3) ^ ((r>>2)&3)
    const int js = tid & 3;
    const int r0 = tid >> 2,  q0 = js ^ (r0 & 3) ^ ((r0 >> 2) & 3);
    const int r1 = r0 + 64,   q1 = js ^ (r1 & 3) ^ ((r1 >> 2) & 3);
    const int p0 = min(nt * 128 + r0, NPIX - 1);
    const int p1 = min(nt * 128 + r1, NPIX - 1);
    const int y0p = p0 / WWID, x0p = p0 - y0p * WWID;
    const int y1p = p1 / WWID, x1p = p1 - y1p * WWID;
    const unsigned short* gb0 = Xt + ((size_t)b * HPIX + y0p * HALO + x0p) * 128 + q0 * 8;
    const unsigned short* gb1 = Xt + ((size_t)b * HPIX + y1p * HALO + x1p) * 128 + q1 * 8;
    unsigned short* lb0[2] = { &Bsh[0][(wv * 64) * 8],       &Bsh[1][(wv * 64) * 8] };
    unsigned short* lb1[2] = { &Bsh[0][(256 + wv * 64) * 8], &Bsh[1][(256 + wv * 64) * 8] };

    // A fragment-linear bases
    const unsigned short* gaw[4];
    #pragma unroll
    for (int tm = 0; tm < 4; tm++) {
        const int m16 = mt * 8 + wrow * 4 + tm;
        gaw[tm] = Apack + ((size_t)m16 * 36 * 64 + ln) * 8;
    }

    // ---- fused routing prologue ----
    if (tid < IN_C) xs[tid] = xse[b * IN_C + tid];
    __syncthreads();
    if (tid < 64) {
        float acc = rb[tid];
        #pragma unroll 8
        for (int c = 0; c < IN_C; c++) acc += xs[c] * rw[tid * IN_C + c];
        rsh[tid] = 0.25f / (1.0f + expf(-acc));    // 2*sigmoid/8
    }
    __syncthreads();

    // issue stage-0 B staging + A frags NOW (latency covered by s-compute)
    cp16(gb0, lb0[0]); cp16(gb1, lb1[0]);
    short8 af[2][4];
    #pragma unroll
    for (int tm = 0; tm < 4; tm++) af[0][tm] = *(const short8*)(gaw[tm]);

    // ---- s-table: ssh[pp][j] = sum_g probs[g,p] * r[g*8+j] ----
    if (tid < 128) {
        const int p = nt * 128 + tid;
        float sj[8] = {0, 0, 0, 0, 0, 0, 0, 0};
        if (p < NPIX) {
            if (use_alpha[0]) {
                float a[8], m = -1e30f;
                #pragma unroll
                for (int g = 0; g < 8; g++) {
                    a[g] = Alpha[((size_t)(b * NG + g)) * NPIX + p];
                    m = fmaxf(m, a[g]);
                }
                float pr[8], sum = 0.f;
                #pragma unroll
                for (int g = 0; g < 8; g++) { pr[g] = expf(a[g] - m); sum += pr[g]; }
                const float inv = 1.f / sum;
                #pragma unroll
                for (int g = 0; g < 8; g++) {
                    const float w = pr[g] * inv;
                    #pragma unroll
                    for (int j = 0; j < 8; j++) sj[j] += w * rsh[g * 8 + j];
                }
            } else {
                const int mg = mask[(size_t)b * NPIX + p];
                #pragma unroll
                for (int j = 0; j < 8; j++) sj[j] = rsh[mg * 8 + j];
            }
        }
        #pragma unroll
        for (int j = 0; j < 8; j++) ssh[tid * 8 + j] = sj[j];
    }

    f32x4 acc[4][4];
    #pragma unroll
    for (int i = 0; i < 4; i++)
        #pragma unroll
        for (int j = 0; j < 4; j++) acc[i][j] = (f32x4){0.f, 0.f, 0.f, 0.f};

    const int jj = lq ^ (lr & 3) ^ ((lr >> 2) & 3);   // B frag slot swizzle

    // ---- main loop: 36 fully-unrolled BK=32 stages, 1 barrier each.
    //      A-frags for stage st+1 are issued in stage st -> consumed after
    //      the next barrier's vmcnt(0) drain (never exposed).
    #pragma unroll
    for (int st = 0; st < 36; st++) {
        const int buf = st & 1;
        __syncthreads();                   // Bsh[buf] + af[st&1] ready
        if (st + 1 < 36) {
            const int nk = (st + 1) * 32;  // compile-time
            const int s  = nk >> 7;
            const int kh = s / 3, kw = s - 3 * kh;
            const int offB = (kh * HALO + kw) * 128 + (nk & 127);
            cp16(gb0 + offB, lb0[buf ^ 1]); cp16(gb1 + offB, lb1[buf ^ 1]);
            #pragma unroll
            for (int tm = 0; tm < 4; tm++)
                af[(st + 1) & 1][tm] = *(const short8*)(gaw[tm] + (size_t)(st + 1) * 512);
        }
        short8 bfr[4];
        #pragma unroll
        for (int tn = 0; tn < 4; tn++) {
            const int row = wcol * 64 + tn * 16 + lr;
            bfr[tn] = *(const short8*)&Bsh[buf][(row * 4 + jj) * 8];
        }
        #pragma unroll
        for (int tm = 0; tm < 4; tm++)
            #pragma unroll
            for (int tn = 0; tn < 4; tn++)
                acc[tm][tn] = __builtin_amdgcn_mfma_f32_16x16x32_bf16(
                    af[st & 1][tm], bfr[tn], acc[tm][tn], 0, 0, 0);
    }

    // ---- epilogue: rows m -> j = (lq&1)*4+reg, o_off = lq>>1; s from LDS ----
    const int j0 = (lq & 1) * 4;
    const int oo = lq >> 1;
    #pragma unroll
    for (int tm = 0; tm < 4; tm++) {
        const int o = mt * 16 + wrow * 8 + tm * 2 + oo;
        const float bo = bias[o];
        #pragma unroll
        for (int tn = 0; tn < 4; tn++) {
            const int pp = wcol * 64 + tn * 16 + lr;
            const int p = nt * 128 + pp;
            const f32x4 sv = *(const f32x4*)&ssh[pp * 8 + j0];
            const f32x4 a = acc[tm][tn];
            float part = a.x * sv.x + a.y * sv.y + a.z * sv.z + a.w * sv.w;
            float tot = part + __shfl_xor(part, 16);
            if ((lq & 1) == 0 && p < NPIX)
                out[((size_t)b * OUT_C + o) * NPIX + p] = tot + bo;
        }
    }
}

extern "C" void kernel_launch(void* const* d_in, const int* in_sizes, int n_in,
                              void* d_out, int out_size, void* d_ws, size_t ws_size,
                              hipStream_t stream) {
    const float* inputs = (const float*)d_in[0];
    const int*   mask   = (const int*)d_in[1];
    const float* Alpha  = (const float*)d_in[2];
    const float* wtmpl  = (const float*)d_in[3];
    const float* rw     = (const float*)d_in[4];
    const float* rb     = (const float*)d_in[5];
    const float* bias   = (const float*)d_in[6];
    const int*   ua     = (const int*)d_in[7];
    float* out = (float*)d_out;

    char* ws = (char*)d_ws;
    unsigned short* Xt  = (unsigned short*)ws;                  // 8*3364*128*2 = 6,889,472
    unsigned short* Apk = (unsigned short*)(ws + 6889472);      // 1024*1152*2  = 2,359,296
    float*          xse = (float*)(ws + 9248768);               // 1024*4

    prep_kernel<<<1376, 256, 0, stream>>>(inputs, wtmpl, xse, Apk, Xt);
    gemm_kernel<<<1600, 256, 0, stream>>>(Apk, Xt, xse, rw, rb, Alpha, mask, ua, bias, out);
}

// Round 10
// 165.626 us; speedup vs baseline: 1.0373x; 1.0373x over previous
//
#include <hip/hip_runtime.h>
#include <stdint.h>

#define IN_C   128
#define OUT_C  128
#define KTOT   1152      // IN_C*3*3
#define NG     8
#define NW     8
#define NB     8
#define HH     56
#define WWID   56
#define NPIX   3136
#define PPAD   3200
#define MTOT   1024      // OUT_C*NW
#define HALO   58        // 56 + zero border on each side
#define HPIX   (HALO*HALO)   // 3364

// k-order SPATIAL-MAJOR: k' = s*128 + c, s = kh*3+kw.
// B gathered from zero-halo Xt[b][58*58][128c] bf16 via LDS: 4 x 8KB buffers,
// ONE barrier per 2 stages (18 drains/block vs 36 in R7's best).
// A pre-packed FRAGMENT-LINEAR Apack[m16][kt][lq][lr][8e]; direct global->VGPR,
// ping-pong reloaded after consumption -> always barrier-protected.

typedef __attribute__((ext_vector_type(8))) short short8;
typedef __attribute__((ext_vector_type(8))) unsigned short ushort8;
typedef __attribute__((ext_vector_type(4))) float f32x4;

__device__ __forceinline__ unsigned short f2bf(float f) {
    unsigned u = __float_as_uint(f);
    u += 0x7FFF + ((u >> 16) & 1);          // round-to-nearest-even
    return (unsigned short)(u >> 16);
}

__device__ __forceinline__ void cp16(const unsigned short* g, unsigned short* l) {
    __builtin_amdgcn_global_load_lds(
        (const __attribute__((address_space(1))) unsigned int*)g,
        (__attribute__((address_space(3))) unsigned int*)l,
        16, 0, 0);
}

// ---------- 1) fused prep: gap (0..1023) | tconv/pack (1024..1151) | transpose (1152..1375) ----------
__global__ __launch_bounds__(256) void prep_kernel(const float* __restrict__ in,
                                                   const float* __restrict__ T,
                                                   float* __restrict__ xse,
                                                   unsigned short* __restrict__ Apack,
                                                   unsigned short* __restrict__ Xt) {
    __shared__ __align__(16) unsigned char smem[32768];   // 32 KB
    const int blk = blockIdx.x;
    const int t = threadIdx.x;

    if (blk < 1024) {
        // ---- global average pool: xse[b,c] ----
        const float* src = in + (size_t)blk * NPIX;
        float s = 0.f;
        for (int i = t; i < NPIX / 4; i += 256) {
            float4 v = ((const float4*)src)[i];
            s += v.x + v.y + v.z + v.w;
        }
        #pragma unroll
        for (int off = 32; off; off >>= 1) s += __shfl_down(s, off);
        float* ws4 = (float*)smem;
        if ((t & 63) == 0) ws4[t >> 6] = s;
        __syncthreads();
        if (t == 0)
            xse[blk] = (ws4[0] + ws4[1] + ws4[2] + ws4[3]) * (1.0f / (float)NPIX);
        return;
    }
    if (blk < 1152) {
        // ---- tconv+pack: block per o. T[o][k][j] slab -> bf16 LDS (18 KB) ->
        //      fragment-linear Apack[m16][kt][lq][lr][8e].
        unsigned short* lh = (unsigned short*)smem;  // 9216 bf16 = 18 KB
        const int o = blk - 1024;
        const float* To = T + (size_t)o * 9216;
        #pragma unroll
        for (int it = 0; it < 9; it++) {
            const int f = it * 256 + t;              // 0..2303 float4 units
            const float4 v = ((const float4*)To)[f];
            ushort4 h;
            h.x = f2bf(v.x); h.y = f2bf(v.y); h.z = f2bf(v.z); h.w = f2bf(v.w);
            *(ushort4*)&lh[f * 4] = h;
        }
        __syncthreads();
        const int m16b = o >> 1;
        const int lrb = (o & 1) * 8;
        #pragma unroll
        for (int it = 0; it < 5; it++) {
            const int ch = it * 256 + t;             // 0..1151: ch = kc*8 + j
            if (ch < 1152) {
                const int j = ch & 7, kc = ch >> 3;  // kc = k-octet 0..143
                const int s = kc >> 4, c0 = (kc & 15) << 3;
                const int kt = kc >> 2, lq = kc & 3;
                ushort8 v;
                #pragma unroll
                for (int i = 0; i < 8; i++)
                    v[i] = lh[((c0 + i) * 9 + s) * 8 + j];
                const size_t off = ((((size_t)m16b * 36 + kt) * 4 + lq) * 16 + lrb + j) * 8;
                *(ushort8*)&Apack[off] = v;
            }
        }
        return;
    }
    // ---- transpose: in[b][c][y][x] fp32 -> Xt[b][(y+1)*58+(x+1)][c] bf16, zero halo ----
    unsigned short* tile = (unsigned short*)smem;    // 32 KB, [c][pix 0..112)
    const int idx = blk - 1152;                      // 0..223
    const int yt = idx % 28;
    const int b  = idx / 28;
    const int y0 = yt * 2;

    #pragma unroll
    for (int it = 0; it < 14; it++) {
        const int f = it * 256 + t;
        const int c = f / 28;
        const int rem = f - c * 28;
        const int y = rem / 14;
        const int x4 = rem - y * 14;
        const float4 v = *(const float4*)(in + ((size_t)(b * IN_C + c)) * NPIX
                                          + (y0 + y) * WWID + x4 * 4);
        unsigned short bf0 = f2bf(v.x), bf1 = f2bf(v.y), bf2 = f2bf(v.z), bf3 = f2bf(v.w);
        const int ppb = (y * WWID + x4 * 4) ^ (((c >> 3) & 15) << 2);
        uint2 pk;
        pk.x = (unsigned)bf0 | ((unsigned)bf1 << 16);
        pk.y = (unsigned)bf2 | ((unsigned)bf3 << 16);
        *(uint2*)&tile[c * 128 + ppb] = pk;
    }
    __syncthreads();

    #pragma unroll
    for (int it = 0; it < 7; it++) {
        const int ch = it * 256 + t;
        const int oct = ch & 15;
        const int pp = ch >> 4;
        const int sw = oct << 2;
        ushort8 v;
        #pragma unroll
        for (int i = 0; i < 8; i++)
            v[i] = tile[(oct * 8 + i) * 128 + (pp ^ sw)];
        const int y2 = (pp >= WWID) ? 1 : 0;
        const int xg = pp - y2 * WWID;
        const size_t hp = (size_t)b * HPIX + (y0 + y2 + 1) * HALO + (xg + 1);
        *(ushort8*)&Xt[hp * 128 + oct * 8] = v;
    }

    if (t < 64) {   // halo columns xx=0,57 for this block's two rows
        const int pi = t >> 4, oct = t & 15;
        const int yy = y0 + 1 + (pi >> 1);
        const int xx = (pi & 1) * 57;
        *(ushort8*)&Xt[((size_t)b * HPIX + yy * HALO + xx) * 128 + oct * 8] =
            (ushort8){0, 0, 0, 0, 0, 0, 0, 0};
    }
    if (yt == 0 || yt == 27) {   // halo rows yy=0 / 57
        const int yy = (yt == 0) ? 0 : 57;
        #pragma unroll
        for (int it = 0; it < 4; it++) {
            const int ch = it * 256 + t;
            if (ch < 928) {
                const int xx = ch >> 4, oct = ch & 15;
                *(ushort8*)&Xt[((size_t)b * HPIX + yy * HALO + xx) * 128 + oct * 8] =
                    (ushort8){0, 0, 0, 0, 0, 0, 0, 0};
            }
        }
    }
}

// ---------- 2) s_kernel (routing fused): s[b][p][j] = sum_g probs[b,g,p] * r[b,g*8+j] ----------
__global__ __launch_bounds__(256) void s_kernel(const float* __restrict__ Alpha,
                                                const int* __restrict__ mask,
                                                const float* __restrict__ xse,
                                                const float* __restrict__ rw,
                                                const float* __restrict__ rb,
                                                const int* __restrict__ use_alpha,
                                                float* __restrict__ Sws) {
    const int b = blockIdx.y;
    const int t = threadIdx.x;
    const int p = blockIdx.x * 256 + t;
    __shared__ float xs[IN_C];
    __shared__ float rsh[64];
    if (t < IN_C) xs[t] = xse[b * IN_C + t];
    __syncthreads();
    if (t < 64) {
        float acc = rb[t];
        #pragma unroll 8
        for (int c = 0; c < IN_C; c++) acc += xs[c] * rw[t * IN_C + c];
        rsh[t] = 0.25f / (1.0f + expf(-acc));        // 2*sigmoid/8
    }
    __syncthreads();
    if (p >= PPAD) return;
    float sj[8] = {0, 0, 0, 0, 0, 0, 0, 0};
    if (p < NPIX) {
        float pr[8];
        if (use_alpha[0]) {
            float a[8], m = -1e30f;
            #pragma unroll
            for (int g = 0; g < 8; g++) {
                a[g] = Alpha[((size_t)(b * NG + g)) * NPIX + p];
                m = fmaxf(m, a[g]);
            }
            float sum = 0.f;
            #pragma unroll
            for (int g = 0; g < 8; g++) { pr[g] = expf(a[g] - m); sum += pr[g]; }
            float inv = 1.f / sum;
            #pragma unroll
            for (int g = 0; g < 8; g++) pr[g] *= inv;
        } else {
            int mg = mask[(size_t)b * NPIX + p];
            #pragma unroll
            for (int g = 0; g < 8; g++) pr[g] = (g == mg) ? 1.f : 0.f;
        }
        #pragma unroll
        for (int g = 0; g < 8; g++)
            #pragma unroll
            for (int j = 0; j < 8; j++) sj[j] += pr[g] * rsh[g * 8 + j];
    }
    float* dst = Sws + ((size_t)b * PPAD + p) * 8;
    *(f32x4*)dst = (f32x4){sj[0], sj[1], sj[2], sj[3]};
    *(f32x4*)(dst + 4) = (f32x4){sj[4], sj[5], sj[6], sj[7]};
}

// ---------- 3) main GEMM + blend epilogue ----------
// 36 BK=32 stages processed in 18 PAIRS: 4 B-buffers, one barrier per pair.
// Prefetch both tiles of pair p+1 at top of pair p; A-frags reloaded after
// consumption, consumed after the next barrier (never exposed).
__global__ __launch_bounds__(256) void gemm_kernel(const unsigned short* __restrict__ Apack,
                                                   const unsigned short* __restrict__ Xt,
                                                   const float* __restrict__ Sws,
                                                   const float* __restrict__ bias,
                                                   float* __restrict__ out) {
    __shared__ __align__(16) unsigned short Bsh[4][512 * 8];   // 4 x 8 KB
    const int tid = threadIdx.x;
    const int wv = tid >> 6, ln = tid & 63;
    const int lq = ln >> 4, lr = ln & 15;
    const int wrow = wv >> 1, wcol = wv & 1;

    const int lid = blockIdx.x;            // 0..1599
    const int b   = lid & 7;               // XCD = b
    const int sl  = lid >> 3;              // 0..199
    const int mt  = sl & 7;
    const int nt  = sl >> 3;               // 0..24

    f32x4 acc[4][4];
    #pragma unroll
    for (int i = 0; i < 4; i++)
        #pragma unroll
        for (int j = 0; j < 4; j++) acc[i][j] = (f32x4){0.f, 0.f, 0.f, 0.f};

    // B staging: chunk (r, slot js) holds octet q = js ^ (r&3) ^ ((r>>2)&3)
    const int js = tid & 3;
    const int r0 = tid >> 2,  q0 = js ^ (r0 & 3) ^ ((r0 >> 2) & 3);
    const int r1 = r0 + 64,   q1 = js ^ (r1 & 3) ^ ((r1 >> 2) & 3);
    const int p0 = min(nt * 128 + r0, NPIX - 1);
    const int p1 = min(nt * 128 + r1, NPIX - 1);
    const int y0p = p0 / WWID, x0p = p0 - y0p * WWID;
    const int y1p = p1 / WWID, x1p = p1 - y1p * WWID;
    const unsigned short* gb0 = Xt + ((size_t)b * HPIX + y0p * HALO + x0p) * 128 + q0 * 8;
    const unsigned short* gb1 = Xt + ((size_t)b * HPIX + y1p * HALO + x1p) * 128 + q1 * 8;
    unsigned short* lbA[4];   // per-buffer LDS target for chunk0 (chunk1 = +256*8)
    #pragma unroll
    for (int i = 0; i < 4; i++) lbA[i] = &Bsh[i][(wv * 64) * 8];

    // A fragment-linear bases
    const unsigned short* gaw[4];
    #pragma unroll
    for (int tm = 0; tm < 4; tm++) {
        const int m16 = mt * 8 + wrow * 4 + tm;
        gaw[tm] = Apack + ((size_t)m16 * 36 * 64 + ln) * 8;
    }

    // frag-read slot swizzle: j' = lq ^ (lr&3) ^ ((lr>>2)&3)
    const int jj = lq ^ (lr & 3) ^ ((lr >> 2) & 3);

    // prologue: tiles 0,1 -> buf0,buf1 (stage1 offB = 32); A frags stages 0,1
    cp16(gb0, lbA[0]); cp16(gb1, lbA[0] + 256 * 8);
    cp16(gb0 + 32, lbA[1]); cp16(gb1 + 32, lbA[1] + 256 * 8);
    short8 af[2][4];
    #pragma unroll
    for (int tm = 0; tm < 4; tm++) af[0][tm] = *(const short8*)(gaw[tm]);
    #pragma unroll
    for (int tm = 0; tm < 4; tm++) af[1][tm] = *(const short8*)(gaw[tm] + 512);

    #pragma unroll 1
    for (int pr = 0; pr < 18; pr++) {
        __syncthreads();                   // tiles 2pr,2pr+1 + af[0],af[1] ready
        const int st2 = pr * 2 + 2, st3 = pr * 2 + 3;
        if (pr < 17) {                     // prefetch pair pr+1 B tiles
            const int nk2 = st2 * 32, s2 = nk2 >> 7;
            const int kh2 = s2 / 3, kw2 = s2 - 3 * kh2;
            const int off2 = (kh2 * HALO + kw2) * 128 + (nk2 & 127);
            const int nk3 = st3 * 32, s3 = nk3 >> 7;
            const int kh3 = s3 / 3, kw3 = s3 - 3 * kh3;
            const int off3 = (kh3 * HALO + kw3) * 128 + (nk3 & 127);
            unsigned short* d2 = lbA[st2 & 3];
            unsigned short* d3 = lbA[st3 & 3];
            cp16(gb0 + off2, d2); cp16(gb1 + off2, d2 + 256 * 8);
            cp16(gb0 + off3, d3); cp16(gb1 + off3, d3 + 256 * 8);
        }
        // ---- stage 2pr: buffer (2pr)&3, af[0] ----
        const int bufa = (pr & 1) * 2;
        {
            short8 bfr[4];
            #pragma unroll
            for (int tn = 0; tn < 4; tn++) {
                const int row = wcol * 64 + tn * 16 + lr;
                bfr[tn] = *(const short8*)&Bsh[bufa][(row * 4 + jj) * 8];
            }
            #pragma unroll
            for (int tm = 0; tm < 4; tm++)
                #pragma unroll
                for (int tn = 0; tn < 4; tn++)
                    acc[tm][tn] = __builtin_amdgcn_mfma_f32_16x16x32_bf16(
                        af[0][tm], bfr[tn], acc[tm][tn], 0, 0, 0);
        }
        if (pr < 17) {                     // reload af[0] <- stage 2pr+2
            #pragma unroll
            for (int tm = 0; tm < 4; tm++)
                af[0][tm] = *(const short8*)(gaw[tm] + (size_t)st2 * 512);
        }
        // ---- stage 2pr+1: buffer (2pr+1)&3, af[1] ----
        {
            short8 bfr[4];
            #pragma unroll
            for (int tn = 0; tn < 4; tn++) {
                const int row = wcol * 64 + tn * 16 + lr;
                bfr[tn] = *(const short8*)&Bsh[bufa + 1][(row * 4 + jj) * 8];
            }
            #pragma unroll
            for (int tm = 0; tm < 4; tm++)
                #pragma unroll
                for (int tn = 0; tn < 4; tn++)
                    acc[tm][tn] = __builtin_amdgcn_mfma_f32_16x16x32_bf16(
                        af[1][tm], bfr[tn], acc[tm][tn], 0, 0, 0);
        }
        if (pr < 17) {                     // reload af[1] <- stage 2pr+3
            #pragma unroll
            for (int tm = 0; tm < 4; tm++)
                af[1][tm] = *(const short8*)(gaw[tm] + (size_t)st3 * 512);
        }
    }

    // epilogue: rows m -> j = (lq&1)*4+reg, o_off = lq>>1
    const int j0 = (lq & 1) * 4;
    const int oo = lq >> 1;
    #pragma unroll
    for (int tm = 0; tm < 4; tm++) {
        const int o = mt * 16 + wrow * 8 + tm * 2 + oo;
        const float bo = bias[o];
        #pragma unroll
        for (int tn = 0; tn < 4; tn++) {
            const int p = nt * 128 + wcol * 64 + tn * 16 + lr;
            const f32x4 sv = *(const f32x4*)&Sws[((size_t)b * PPAD + p) * 8 + j0];
            const f32x4 a = acc[tm][tn];
            float part = a.x * sv.x + a.y * sv.y + a.z * sv.z + a.w * sv.w;
            float tot = part + __shfl_xor(part, 16);
            if ((lq & 1) == 0 && p < NPIX)
                out[((size_t)b * OUT_C + o) * NPIX + p] = tot + bo;
        }
    }
}

extern "C" void kernel_launch(void* const* d_in, const int* in_sizes, int n_in,
                              void* d_out, int out_size, void* d_ws, size_t ws_size,
                              hipStream_t stream) {
    const float* inputs = (const float*)d_in[0];
    const int*   mask   = (const int*)d_in[1];
    const float* Alpha  = (const float*)d_in[2];
    const float* wtmpl  = (const float*)d_in[3];
    const float* rw     = (const float*)d_in[4];
    const float* rb     = (const float*)d_in[5];
    const float* bias   = (const float*)d_in[6];
    const int*   ua     = (const int*)d_in[7];
    float* out = (float*)d_out;

    char* ws = (char*)d_ws;
    unsigned short* Xt  = (unsigned short*)ws;                  // 8*3364*128*2 = 6,889,472
    unsigned short* Apk = (unsigned short*)(ws + 6889472);      // 1024*1152*2  = 2,359,296
    float*          Sws = (float*)(ws + 9248768);               // 8*3200*8*4   =   819,200
    float*          xse = (float*)(ws + 10067968);              // 1024*4

    prep_kernel<<<1376, 256, 0, stream>>>(inputs, wtmpl, xse, Apk, Xt);
    s_kernel<<<dim3(13, NB), 256, 0, stream>>>(Alpha, mask, xse, rw, rb, ua, Sws);
    gemm_kernel<<<1600, 256, 0, stream>>>(Apk, Xt, Sws, bias, out);
}